// Round 1
// baseline (1149.678 us; speedup 1.0000x reference)
//
#include <hip/hip_runtime.h>
#include <hip/hip_bf16.h>
#include <stdint.h>

// RoPEDemoAttention on MI355X (gfx950)
// B=4, S=4096, D=256. fp32 in/out.
// K0: split fp32 -> bf16 hi/lo (x, wq, wk, wv)
// K1: Q/K/V = X @ W^T via 3-pass split-bf16 MFMA; RoPE on Q,K in fp32; store
//     qh/ql/kh/kl bf16 row-major [b][s][d] and V transposed vt[b][d][s] bf16.
// K2: S^T = K*Q^T per (b, 64-q-tile); e = exp(s/16) unnormalized -> weights
//     region of d_out; rowsums -> ws. K-tiles staged via global_load_lds with
//     XOR swizzle (pre-swizzled global source).
// K3: read e back, normalize in place (final weights), PV via bf16 MFMA
//     (V^T B-frags direct from global), write output.

#define B_ 4
#define S_ 4096
#define D_ 256
#define NQ 4194304   // B_*S_*D_
#define NW 65536     // D_*D_

typedef __attribute__((ext_vector_type(4))) float f32x4;
typedef __attribute__((ext_vector_type(8))) short short8;
typedef __attribute__((ext_vector_type(4))) short short4v;

__device__ __forceinline__ short f2bf(float f) {
  unsigned u = __builtin_bit_cast(unsigned, f);
  u += 0x7fffu + ((u >> 16) & 1u);   // RNE
  return (short)(u >> 16);
}
__device__ __forceinline__ float bf2f(short h) {
  unsigned u = ((unsigned)(unsigned short)h) << 16;
  return __builtin_bit_cast(float, u);
}

__device__ __forceinline__ void gload16(const void* g, void* l) {
  __builtin_amdgcn_global_load_lds(
      (const __attribute__((address_space(1))) unsigned*)g,
      (__attribute__((address_space(3))) unsigned*)l, 16, 0, 0);
}

// ---------------------------------------------------------------- K0: split
__global__ __launch_bounds__(256) void k0_split(
    const float* __restrict__ x, const float* __restrict__ wq,
    const float* __restrict__ wk, const float* __restrict__ wv,
    short* __restrict__ xh, short* __restrict__ xl,
    short* __restrict__ wh, short* __restrict__ wl) {
  int idx = blockIdx.x * 256 + threadIdx.x;   // exact grid: NQ + 3*NW threads
  float v; short *ph, *pl; int o;
  if (idx < NQ) {
    v = x[idx]; ph = xh; pl = xl; o = idx;
  } else {
    int r = idx - NQ;
    int m = r >> 16;       // /NW
    int e = r & (NW - 1);
    const float* w = (m == 0) ? wq : (m == 1) ? wk : wv;
    v = w[e]; ph = wh; pl = wl; o = r;
  }
  short hi = f2bf(v);
  ph[o] = hi;
  pl[o] = f2bf(v - bf2f(hi));
}

// ------------------------------------------------------- K1: proj + RoPE
__global__ __launch_bounds__(256) void k1_proj(
    const short* __restrict__ xh, const short* __restrict__ xl,
    const short* __restrict__ wh, const short* __restrict__ wl,
    short* __restrict__ qh, short* __restrict__ ql,
    short* __restrict__ kh, short* __restrict__ kl,
    short* __restrict__ vt) {
  const int m = blockIdx.y;                 // 0=q 1=k 2=v
  const int b = blockIdx.x >> 6;
  const int sbase = (blockIdx.x & 63) << 6; // 64-row tile
  const int tid = threadIdx.x;
  const int w = tid >> 6;
  const int lane = tid & 63;
  const int lr = lane & 15;
  const int g = lane >> 4;

  const int srow = sbase + w * 16 + lr;     // A-frag row
  const short* xhp = xh + ((size_t)(b * S_ + srow)) * D_;
  const short* xlp = xl + ((size_t)(b * S_ + srow)) * D_;
  const short* whm = wh + m * NW;
  const short* wlm = wl + m * NW;

  f32x4 acc[16];
#pragma unroll
  for (int i = 0; i < 16; ++i) acc[i] = (f32x4)0.f;

#pragma unroll
  for (int dc = 0; dc < 8; ++dc) {
    const int d = dc * 32 + g * 8;
    short8 ah = *(const short8*)(xhp + d);
    short8 al = *(const short8*)(xlp + d);
#pragma unroll
    for (int ct = 0; ct < 16; ++ct) {
      const int e = ct * 16 + lr;
      short8 bh = *(const short8*)(whm + e * D_ + d);
      short8 bl = *(const short8*)(wlm + e * D_ + d);
      acc[ct] = __builtin_amdgcn_mfma_f32_16x16x32_bf16(ah, bh, acc[ct], 0, 0, 0);
      acc[ct] = __builtin_amdgcn_mfma_f32_16x16x32_bf16(ah, bl, acc[ct], 0, 0, 0);
      acc[ct] = __builtin_amdgcn_mfma_f32_16x16x32_bf16(al, bh, acc[ct], 0, 0, 0);
    }
  }

  const int s0 = sbase + w * 16 + g * 4;    // C/D row base
  if (m == 2) {
    // store V transposed: vt[b][e][s], 4 consecutive s per lane -> 8B store
#pragma unroll
    for (int ct = 0; ct < 16; ++ct) {
      const int e = ct * 16 + lr;
      short4v pk;
#pragma unroll
      for (int r = 0; r < 4; ++r) pk[r] = f2bf(acc[ct][r]);
      *(short4v*)(vt + ((size_t)(b * D_ + e)) * S_ + s0) = pk;
    }
  } else {
    short* oh = (m == 0) ? qh : kh;
    short* ol = (m == 0) ? ql : kl;
#pragma unroll
    for (int ct = 0; ct < 16; ++ct) {
      const int e = ct * 16 + lr;
      // angle(s, e) = s * 10000^(-(e mod 128)/128); ln(10000)/128:
      const float invf = expf(-0.07195578415606394f * (float)(e & 127));
      const float sgn = (e & 1) ? 1.0f : -1.0f;  // rotate_half sign
#pragma unroll
      for (int r = 0; r < 4; ++r) {
        float v = acc[ct][r];
        float p = __shfl_xor(v, 1, 64);          // partner e^1, same s
        float ang = (float)(s0 + r) * invf;
        float sn, cs;
        sincosf(ang, &sn, &cs);
        float q2 = v * cs + sgn * p * sn;
        short hi = f2bf(q2);
        size_t off = ((size_t)(b * S_ + s0 + r)) * D_ + e;
        oh[off] = hi;
        ol[off] = f2bf(q2 - bf2f(hi));
      }
    }
  }
}

// -------------------------------------- K2: scores S^T = K Q^T, e = exp(s/16)
__global__ __launch_bounds__(256, 1) void k2_scores(
    const short* __restrict__ qh, const short* __restrict__ ql,
    const short* __restrict__ kh, const short* __restrict__ kl,
    float* __restrict__ wts, float* __restrict__ lsum) {
  __shared__ __align__(16) char sbuf[65536];   // Khi [64][256]bf16 | Klo
  __shared__ float part[2][64];

  const int bid = blockIdx.x;
  const int swz = (bid & 7) * 32 + (bid >> 3); // XCD-contiguous chunks (256=8*32)
  const int b = swz >> 6;
  const int qbase = (swz & 63) << 6;
  const int tid = threadIdx.x;
  const int w = tid >> 6;
  const int lane = tid & 63;
  const int lr = lane & 15;
  const int g = lane >> 4;
  const int wq2 = w & 1;   // which 32 q-rows
  const int wk2 = w >> 1;  // which 32 keys of the 64-key tile

  // Q fragments (B-operand), cached in registers for all 64 k-tiles
  short8 qfh[2][8], qfl[2][8];
#pragma unroll
  for (int qt = 0; qt < 2; ++qt) {
    const int qrow = qbase + wq2 * 32 + qt * 16 + lr;
    const short* ph = qh + ((size_t)(b * S_ + qrow)) * D_;
    const short* pl = ql + ((size_t)(b * S_ + qrow)) * D_;
#pragma unroll
    for (int dc = 0; dc < 8; ++dc) {
      qfh[qt][dc] = *(const short8*)(ph + dc * 32 + g * 8);
      qfl[qt][dc] = *(const short8*)(pl + dc * 32 + g * 8);
    }
  }

  f32x4 acc[2][2];
#pragma unroll
  for (int rt = 0; rt < 2; ++rt)
#pragma unroll
    for (int qt = 0; qt < 2; ++qt) acc[rt][qt] = (f32x4)0.f;
  float rs[2] = {0.f, 0.f};

  const char* khb = (const char*)(kh + (size_t)b * S_ * D_);
  const char* klb = (const char*)(kl + (size_t)b * S_ * D_);
  const int keyl = wk2 * 32 + lr;      // local key row of A-frag (+16*rt)
  const int swx = (lane & 7) << 4;     // XOR-swizzle term: (key&7)<<4

  for (int kt = 0; kt < 64; ++kt) {
    __syncthreads();  // previous tile's LDS reads done
    {
      const char* sh = khb + (size_t)kt * 64 * D_ * 2;
      const char* sl = klb + (size_t)kt * 64 * D_ * 2;
#pragma unroll
      for (int i = 0; i < 8; ++i) {
        const int p = i * 4096 + tid * 16;              // linear LDS dest
        const int xo = p ^ (((p >> 9) & 7) << 4);       // pre-swizzled source
        gload16(sh + xo, sbuf + p);
        gload16(sl + xo, sbuf + 32768 + p);
      }
    }
    __syncthreads();  // compiler drains vmcnt before barrier

#pragma unroll
    for (int dc = 0; dc < 8; ++dc) {
      short8 afh[2], afl[2];
#pragma unroll
      for (int rt = 0; rt < 2; ++rt) {
        const int x = (keyl + rt * 16) * 512 + dc * 64 + g * 16;
        const int p = x ^ swx;
        afh[rt] = *(const short8*)(sbuf + p);
        afl[rt] = *(const short8*)(sbuf + 32768 + p);
      }
#pragma unroll
      for (int rt = 0; rt < 2; ++rt)
#pragma unroll
        for (int qt = 0; qt < 2; ++qt) {
          acc[rt][qt] = __builtin_amdgcn_mfma_f32_16x16x32_bf16(afh[rt], qfh[qt][dc], acc[rt][qt], 0, 0, 0);
          acc[rt][qt] = __builtin_amdgcn_mfma_f32_16x16x32_bf16(afh[rt], qfl[qt][dc], acc[rt][qt], 0, 0, 0);
          acc[rt][qt] = __builtin_amdgcn_mfma_f32_16x16x32_bf16(afl[rt], qfh[qt][dc], acc[rt][qt], 0, 0, 0);
        }
    }

    // epilogue: e = exp(s/16), write unnormalized, accumulate rowsums
#pragma unroll
    for (int rt = 0; rt < 2; ++rt)
#pragma unroll
      for (int qt = 0; qt < 2; ++qt) {
        f32x4 e;
#pragma unroll
        for (int r = 0; r < 4; ++r) e[r] = expf(acc[rt][qt][r] * 0.0625f);
        const int qrow = qbase + wq2 * 32 + qt * 16 + lr;
        const int key = kt * 64 + wk2 * 32 + rt * 16 + g * 4;
        *(f32x4*)(wts + ((size_t)(b * S_ + qrow)) * S_ + key) = e;
        rs[qt] += e[0] + e[1] + e[2] + e[3];
        acc[rt][qt] = (f32x4)0.f;
      }
  }

  // reduce rowsums across the 4 g-groups (lanes sharing lane&15)
#pragma unroll
  for (int qt = 0; qt < 2; ++qt) {
    rs[qt] += __shfl_xor(rs[qt], 16, 64);
    rs[qt] += __shfl_xor(rs[qt], 32, 64);
  }
  if (lane < 16) {
    part[wk2][wq2 * 32 + lane] = rs[0];
    part[wk2][wq2 * 32 + 16 + lane] = rs[1];
  }
  __syncthreads();
  if (tid < 64) lsum[b * S_ + qbase + tid] = part[0][tid] + part[1][tid];
}

// ------------------------------------ K3: normalize weights in place + PV
__global__ __launch_bounds__(256, 1) void k3_pv(
    float* __restrict__ wts, const float* __restrict__ lsum,
    const short* __restrict__ vt, float* __restrict__ out) {
  const int bid = blockIdx.x;
  const int swz = (bid & 7) * 32 + (bid >> 3);
  const int b = swz >> 6;
  const int qbase = (swz & 63) << 6;
  const int tid = threadIdx.x;
  const int w = tid >> 6;
  const int lane = tid & 63;
  const int lr = lane & 15;
  const int g = lane >> 4;

  const int qrow = qbase + w * 16 + lr;     // A-frag row
  const float rinv = 1.0f / lsum[b * S_ + qrow];
  float* wrow = wts + ((size_t)(b * S_ + qrow)) * S_;
  const short* vtb = vt + (size_t)b * D_ * S_;

  f32x4 acc[16];
#pragma unroll
  for (int i = 0; i < 16; ++i) acc[i] = (f32x4)0.f;

  for (int kc = 0; kc < 128; ++kc) {
    const int key0 = kc * 32 + g * 8;
    f32x4 e0 = *(const f32x4*)(wrow + key0);
    f32x4 e1 = *(const f32x4*)(wrow + key0 + 4);
    e0 *= rinv; e1 *= rinv;
    *(f32x4*)(wrow + key0) = e0;            // final normalized weights
    *(f32x4*)(wrow + key0 + 4) = e1;
    short8 a;
    a[0] = f2bf(e0[0]); a[1] = f2bf(e0[1]); a[2] = f2bf(e0[2]); a[3] = f2bf(e0[3]);
    a[4] = f2bf(e1[0]); a[5] = f2bf(e1[1]); a[6] = f2bf(e1[2]); a[7] = f2bf(e1[3]);
#pragma unroll
    for (int dt = 0; dt < 16; ++dt) {
      short8 bf = *(const short8*)(vtb + ((size_t)(dt * 16 + lr)) * S_ + key0);
      acc[dt] = __builtin_amdgcn_mfma_f32_16x16x32_bf16(a, bf, acc[dt], 0, 0, 0);
    }
  }

  const int s0 = qbase + w * 16 + g * 4;    // C/D row base
  float* ob = out + ((size_t)b * S_) * D_;
#pragma unroll
  for (int dt = 0; dt < 16; ++dt)
#pragma unroll
    for (int r = 0; r < 4; ++r)
      ob[(size_t)(s0 + r) * D_ + dt * 16 + lr] = acc[dt][r];
}

// ---------------------------------------------------------------- launch
extern "C" void kernel_launch(void* const* d_in, const int* in_sizes, int n_in,
                              void* d_out, int out_size, void* d_ws, size_t ws_size,
                              hipStream_t stream) {
  const float* x  = (const float*)d_in[0];
  const float* wq = (const float*)d_in[1];
  const float* wk = (const float*)d_in[2];
  const float* wv = (const float*)d_in[3];

  float* out = (float*)d_out;                    // [B][S][D]
  float* wts = out + (size_t)B_ * S_ * D_;       // [B][S][S]

  // workspace layout (needs ~59.6 MB)
  short* xh = (short*)d_ws;
  short* xl = xh + NQ;
  short* qh = xl + NQ;
  short* ql = qh + NQ;
  short* kh = ql + NQ;
  short* kl = kh + NQ;
  short* vt = kl + NQ;                 // [B][D][S] bf16
  short* wh = vt + NQ;                 // [3][D][D] bf16
  short* wl = wh + 3 * NW;
  float* lsum = (float*)(wl + 3 * NW); // [B][S] fp32

  k0_split<<<dim3((NQ + 3 * NW) / 256), 256, 0, stream>>>(
      x, wq, wk, wv, xh, xl, wh, wl);
  k1_proj<<<dim3(B_ * S_ / 64, 3), 256, 0, stream>>>(
      xh, xl, wh, wl, qh, ql, kh, kl, vt);
  k2_scores<<<dim3(B_ * S_ / 64), 256, 0, stream>>>(
      qh, ql, kh, kl, wts, lsum);
  k3_pv<<<dim3(B_ * S_ / 64), 256, 0, stream>>>(
      wts, lsum, vt, out);
}

// Round 2
// 486.615 us; speedup vs baseline: 2.3626x; 2.3626x over previous
//
#include <hip/hip_runtime.h>
#include <hip/hip_bf16.h>
#include <stdint.h>

// RoPEDemoAttention on MI355X (gfx950)
// B=4, S=4096, D=256. fp32 in/out.
// K0: split fp32 -> bf16 hi/lo (x, wq, wk, wv) + build RoPE cos/sin table.
// K1: Q/K/V = X @ W^T via 3-pass split-bf16 MFMA; RoPE via table; store
//     qh/ql/kh/kl bf16 [b][s][d] and V transposed vt[b][d][s] bf16.
// K2 (fused): per (b, 64-q-tile): scores S^T = K*Q^T (3-pass split),
//     e = exp(s/16) -> LDS e-tile (bf16, swizzled) -> (a) coalesced copy of
//     unnormalized e-bf16 into the TOP HALF of this block's own weights
//     region (scratch), (b) PV accumulate out += e*V from LDS/registers.
//     Epilogue: rowsums -> normalized output write, then a phased in-place
//     sweep converts e-bf16 -> normalized f32 weights (ascending phases so
//     w-row j only overwrites e-rows 2j-64,2j-64+1 which are already done;
//     rows 62,63 pre-copied to LDS).

#define B_ 4
#define S_ 4096
#define D_ 256
#define NQ 4194304   // B_*S_*D_
#define NW 65536     // D_*D_
#define NTAB 524288  // S_*128 table entries (cos,sin pairs)

typedef __attribute__((ext_vector_type(4))) float f32x4;
typedef __attribute__((ext_vector_type(8))) short short8;
typedef __attribute__((ext_vector_type(4))) short short4v;
typedef __attribute__((ext_vector_type(4))) unsigned uint32x4;

__device__ __forceinline__ short f2bf(float f) {
  unsigned u = __builtin_bit_cast(unsigned, f);
  u += 0x7fffu + ((u >> 16) & 1u);   // RNE
  return (short)(u >> 16);
}
__device__ __forceinline__ float bf2f(short h) {
  unsigned u = ((unsigned)(unsigned short)h) << 16;
  return __builtin_bit_cast(float, u);
}

__device__ __forceinline__ void gload16(const void* g, void* l) {
  __builtin_amdgcn_global_load_lds(
      (const __attribute__((address_space(1))) unsigned*)g,
      (__attribute__((address_space(3))) unsigned*)l, 16, 0, 0);
}

// ------------------------------------------------ K0: split + RoPE table
__global__ __launch_bounds__(256) void k0_split(
    const float* __restrict__ x, const float* __restrict__ wq,
    const float* __restrict__ wk, const float* __restrict__ wv,
    short* __restrict__ xh, short* __restrict__ xl,
    short* __restrict__ wh, short* __restrict__ wl,
    float* __restrict__ ctab) {
  int idx = blockIdx.x * 256 + threadIdx.x;  // grid = NQ + 3*NW + NTAB
  if (idx < NQ) {
    float v = x[idx];
    short hi = f2bf(v);
    xh[idx] = hi;
    xl[idx] = f2bf(v - bf2f(hi));
  } else if (idx < NQ + 3 * NW) {
    int r = idx - NQ;
    int m = r >> 16;
    int e = r & (NW - 1);
    const float* w = (m == 0) ? wq : (m == 1) ? wk : wv;
    float v = w[e];
    short hi = f2bf(v);
    wh[r] = hi;
    wl[r] = f2bf(v - bf2f(hi));
  } else {
    int t = idx - NQ - 3 * NW;          // t < NTAB
    int s = t >> 7, j = t & 127;
    float invf = __expf(-0.07195578415606394f * (float)j); // 10000^(-j/128)
    float sn, cs;
    sincosf((float)s * invf, &sn, &cs);
    ctab[2 * t] = cs;
    ctab[2 * t + 1] = sn;
  }
}

// ------------------------------------------------------- K1: proj + RoPE
__global__ __launch_bounds__(256) void k1_proj(
    const short* __restrict__ xh, const short* __restrict__ xl,
    const short* __restrict__ wh, const short* __restrict__ wl,
    const float* __restrict__ ctab,
    short* __restrict__ qh, short* __restrict__ ql,
    short* __restrict__ kh, short* __restrict__ kl,
    short* __restrict__ vt) {
  const int m = blockIdx.y;                 // 0=q 1=k 2=v
  const int b = blockIdx.x >> 6;
  const int sbase = (blockIdx.x & 63) << 6; // 64-row tile
  const int tid = threadIdx.x;
  const int w = tid >> 6;
  const int lane = tid & 63;
  const int lr = lane & 15;
  const int g = lane >> 4;

  const int srow = sbase + w * 16 + lr;     // A-frag row
  const short* xhp = xh + ((size_t)(b * S_ + srow)) * D_;
  const short* xlp = xl + ((size_t)(b * S_ + srow)) * D_;
  const short* whm = wh + m * NW;
  const short* wlm = wl + m * NW;

  f32x4 acc[16];
#pragma unroll
  for (int i = 0; i < 16; ++i) acc[i] = (f32x4)0.f;

#pragma unroll
  for (int dc = 0; dc < 8; ++dc) {
    const int d = dc * 32 + g * 8;
    short8 ah = *(const short8*)(xhp + d);
    short8 al = *(const short8*)(xlp + d);
#pragma unroll
    for (int ct = 0; ct < 16; ++ct) {
      const int e = ct * 16 + lr;
      short8 bh = *(const short8*)(whm + e * D_ + d);
      short8 bl = *(const short8*)(wlm + e * D_ + d);
      acc[ct] = __builtin_amdgcn_mfma_f32_16x16x32_bf16(ah, bh, acc[ct], 0, 0, 0);
      acc[ct] = __builtin_amdgcn_mfma_f32_16x16x32_bf16(ah, bl, acc[ct], 0, 0, 0);
      acc[ct] = __builtin_amdgcn_mfma_f32_16x16x32_bf16(al, bh, acc[ct], 0, 0, 0);
    }
  }

  const int s0 = sbase + w * 16 + g * 4;    // C/D row base
  if (m == 2) {
#pragma unroll
    for (int ct = 0; ct < 16; ++ct) {
      const int e = ct * 16 + lr;
      short4v pk;
#pragma unroll
      for (int r = 0; r < 4; ++r) pk[r] = f2bf(acc[ct][r]);
      *(short4v*)(vt + ((size_t)(b * D_ + e)) * S_ + s0) = pk;
    }
  } else {
    short* oh = (m == 0) ? qh : kh;
    short* ol = (m == 0) ? ql : kl;
#pragma unroll
    for (int ct = 0; ct < 16; ++ct) {
      const int e = ct * 16 + lr;
      const float sgn = (e & 1) ? 1.0f : -1.0f;  // rotate_half sign
#pragma unroll
      for (int r = 0; r < 4; ++r) {
        float v = acc[ct][r];
        float p = __shfl_xor(v, 1, 64);          // partner e^1, same s
        const float2 cs2 = *(const float2*)(ctab + ((size_t)((s0 + r) << 7) + (e & 127)) * 2);
        float q2 = v * cs2.x + sgn * p * cs2.y;
        short hi = f2bf(q2);
        size_t off = ((size_t)(b * S_ + s0 + r)) * D_ + e;
        oh[off] = hi;
        ol[off] = f2bf(q2 - bf2f(hi));
      }
    }
  }
}

// ------------------- K2 fused: scores + e-store + PV + normalize sweep
__global__ __launch_bounds__(512, 2) void k2_fused(
    const short* __restrict__ qh, const short* __restrict__ ql,
    const short* __restrict__ kh, const short* __restrict__ kl,
    const short* __restrict__ vt,
    float* __restrict__ wts, float* __restrict__ out) {
  __shared__ __align__(16) char sbuf[65536];   // Khi [64][256]bf16 | Klo
  __shared__ __align__(16) char etile[8192];   // e bf16 [64][64], swizzled
  __shared__ float part[4][64];
  __shared__ float lsum_l[64];

  const int bid = blockIdx.x;
  const int swz = (bid & 7) * 32 + (bid >> 3); // XCD-contiguous (256 = 8*32)
  const int b = swz >> 6;
  const int qbase = (swz & 63) << 6;
  const int tid = threadIdx.x;
  const int w = tid >> 6;        // 8 waves
  const int lane = tid & 63;
  const int lr = lane & 15;
  const int g = lane >> 4;
  const int wq2 = w & 1;         // scores: which 32 q-rows
  const int wk4 = w >> 1;        // scores: which 16 keys of 64-key tile
  const int qh_pv = w & 1;       // PV: q 32-half
  const int dh_pv = w >> 1;      // PV: d 64-quarter

  // Q hi/lo fragments (B-operand), registers for all 64 k-tiles
  short8 qfh[2][8], qfl[2][8];
#pragma unroll
  for (int qt = 0; qt < 2; ++qt) {
    const int qrow = qbase + wq2 * 32 + qt * 16 + lr;
    const short* ph = qh + ((size_t)(b * S_ + qrow)) * D_;
    const short* pl = ql + ((size_t)(b * S_ + qrow)) * D_;
#pragma unroll
    for (int dc = 0; dc < 8; ++dc) {
      qfh[qt][dc] = *(const short8*)(ph + dc * 32 + g * 8);
      qfl[qt][dc] = *(const short8*)(pl + dc * 32 + g * 8);
    }
  }

  f32x4 acc[2];
  acc[0] = (f32x4)0.f; acc[1] = (f32x4)0.f;
  f32x4 accv[2][4];
#pragma unroll
  for (int qt = 0; qt < 2; ++qt)
#pragma unroll
    for (int dt = 0; dt < 4; ++dt) accv[qt][dt] = (f32x4)0.f;
  float rs[2] = {0.f, 0.f};

  const char* khb = (const char*)(kh + (size_t)b * S_ * D_);
  const char* klb = (const char*)(kl + (size_t)b * S_ * D_);
  const short* vtb = vt + (size_t)b * D_ * S_;
  const int keyl = wk4 * 16 + lr;          // local key row of A-frag
  const int swx = (lane & 7) << 4;         // K-LDS swizzle: (key&7)<<4

  // block's weights region (1 MiB); e-bf16 scratch in its top half
  char* WB = (char*)(wts + ((size_t)(b * S_ + qbase)) * S_);
  char* EB = WB + 524288;

  // prologue: stage K-tile 0 (linear LDS dest, pre-swizzled global source)
  {
#pragma unroll
    for (int i = 0; i < 4; ++i) {
      const int p = i * 8192 + tid * 16;
      const int xo = p ^ (((p >> 9) & 7) << 4);
      gload16(khb + xo, sbuf + p);
      gload16(klb + xo, sbuf + 32768 + p);
    }
  }
  __syncthreads();

  for (int kt = 0; kt < 64; ++kt) {
    // ---- scores: 3-pass split bf16, S^T = K * Q^T
#pragma unroll
    for (int dc = 0; dc < 8; ++dc) {
      const int x = (keyl * 512 + dc * 64 + g * 16) ^ swx;
      short8 afh = *(const short8*)(sbuf + x);
      short8 afl = *(const short8*)(sbuf + 32768 + x);
      acc[0] = __builtin_amdgcn_mfma_f32_16x16x32_bf16(afh, qfh[0][dc], acc[0], 0, 0, 0);
      acc[0] = __builtin_amdgcn_mfma_f32_16x16x32_bf16(afh, qfl[0][dc], acc[0], 0, 0, 0);
      acc[0] = __builtin_amdgcn_mfma_f32_16x16x32_bf16(afl, qfh[0][dc], acc[0], 0, 0, 0);
      acc[1] = __builtin_amdgcn_mfma_f32_16x16x32_bf16(afh, qfh[1][dc], acc[1], 0, 0, 0);
      acc[1] = __builtin_amdgcn_mfma_f32_16x16x32_bf16(afh, qfl[1][dc], acc[1], 0, 0, 0);
      acc[1] = __builtin_amdgcn_mfma_f32_16x16x32_bf16(afl, qfh[1][dc], acc[1], 0, 0, 0);
    }

    // ---- epilogue: e = exp(s/16) -> LDS e-tile (bf16, swizzled) + rowsum
#pragma unroll
    for (int qt = 0; qt < 2; ++qt) {
      f32x4 e;
#pragma unroll
      for (int r = 0; r < 4; ++r) e[r] = __expf(acc[qt][r] * 0.0625f);
      rs[qt] += e[0] + e[1] + e[2] + e[3];
      unsigned lo = (unsigned)(unsigned short)f2bf(e[0]) |
                    ((unsigned)(unsigned short)f2bf(e[1]) << 16);
      unsigned hi2 = (unsigned)(unsigned short)f2bf(e[2]) |
                     ((unsigned)(unsigned short)f2bf(e[3]) << 16);
      const int row = wq2 * 32 + qt * 16 + lr;
      const int colb = (wk4 * 16 + g * 4) * 2;
      const int ad = (row * 128 + colb) ^ ((row & 7) << 4);
      *(uint2*)(etile + ad) = make_uint2(lo, hi2);
      acc[qt] = (f32x4)0.f;
    }
    __syncthreads();   // e-tile complete; scores' sbuf reads done

    // ---- stage next K-tile (overlaps e-copy + PV)
    if (kt < 63) {
      const char* sh = khb + (size_t)(kt + 1) * 64 * D_ * 2;
      const char* sl = klb + (size_t)(kt + 1) * 64 * D_ * 2;
#pragma unroll
      for (int i = 0; i < 4; ++i) {
        const int p = i * 8192 + tid * 16;
        const int xo = p ^ (((p >> 9) & 7) << 4);
        gload16(sh + xo, sbuf + p);
        gload16(sl + xo, sbuf + 32768 + p);
      }
    }

    // ---- coalesced copy of unnormalized e-bf16 into EB (top half of WB)
    {
      const int p = tid * 16;              // 512 thr * 16B = 8 KB
      const int row = p >> 7, cb = p & 127;
      uint32x4 v = *(const uint32x4*)(etile + (p ^ ((row & 7) << 4)));
      *(uint32x4*)(EB + (size_t)row * 8192 + kt * 128 + cb) = v;
    }

    // ---- PV: out += e * V  (A = e-tile from LDS, B = V^T from global/L2)
#pragma unroll
    for (int kk = 0; kk < 2; ++kk) {
      short8 ea0, ea1;
      {
        const int row = qh_pv * 32 + lr;
        ea0 = *(const short8*)(etile + ((row * 128 + kk * 64 + g * 16) ^ ((row & 7) << 4)));
      }
      {
        const int row = qh_pv * 32 + 16 + lr;
        ea1 = *(const short8*)(etile + ((row * 128 + kk * 64 + g * 16) ^ ((row & 7) << 4)));
      }
#pragma unroll
      for (int dt = 0; dt < 4; ++dt) {
        const int d = dh_pv * 64 + dt * 16 + lr;
        short8 vb = *(const short8*)(vtb + (size_t)d * S_ + kt * 64 + kk * 32 + g * 8);
        accv[0][dt] = __builtin_amdgcn_mfma_f32_16x16x32_bf16(ea0, vb, accv[0][dt], 0, 0, 0);
        accv[1][dt] = __builtin_amdgcn_mfma_f32_16x16x32_bf16(ea1, vb, accv[1][dt], 0, 0, 0);
      }
    }
    __syncthreads();  // e-tile reads + staging done before next iteration
  }

  // ---- rowsums -> lsum_l
#pragma unroll
  for (int qt = 0; qt < 2; ++qt) {
    rs[qt] += __shfl_xor(rs[qt], 16, 64);
    rs[qt] += __shfl_xor(rs[qt], 32, 64);
  }
  if (lane < 16) {
    part[wk4][wq2 * 32 + lane] = rs[0];
    part[wk4][wq2 * 32 + 16 + lane] = rs[1];
  }
  __syncthreads();
  if (tid < 64)
    lsum_l[tid] = part[0][tid] + part[1][tid] + part[2][tid] + part[3][tid];
  __syncthreads();

  // ---- copy e rows 62,63 to LDS (their EB copies get overwritten last)
#pragma unroll
  for (int i = 0; i < 2; ++i) {
    const int p = i * 8192 + tid * 16;
    *(uint32x4*)(sbuf + p) = *(const uint32x4*)(EB + (size_t)62 * 8192 + p);
  }

  // ---- normalized output write
  {
    float* ob = out + (size_t)b * S_ * D_;
    float rv[2][4];
#pragma unroll
    for (int qt = 0; qt < 2; ++qt)
#pragma unroll
      for (int r = 0; r < 4; ++r)
        rv[qt][r] = 1.0f / lsum_l[qh_pv * 32 + qt * 16 + g * 4 + r];
#pragma unroll
    for (int qt = 0; qt < 2; ++qt)
#pragma unroll
      for (int dt = 0; dt < 4; ++dt)
#pragma unroll
        for (int r = 0; r < 4; ++r) {
          const int q = qbase + qh_pv * 32 + qt * 16 + g * 4 + r;
          ob[(size_t)q * D_ + dh_pv * 64 + dt * 16 + lr] = accv[qt][dt][r] * rv[qt][r];
        }
  }
  __syncthreads();

  // ---- phased in-place normalize sweep: e-bf16 (EB) -> f32 weights (WB)
  const int pr0[6] = {0, 32, 48, 56, 60, 62};
  const int pr1[6] = {32, 48, 56, 60, 62, 64};
#pragma unroll 1
  for (int ph = 0; ph < 6; ++ph) {
    for (int r = pr0[ph] + w; r < pr1[ph]; r += 8) {
      const float rinv = 1.0f / lsum_l[r];
      const short* erow = (r >= 62) ? (const short*)(sbuf + (size_t)(r - 62) * 8192)
                                    : (const short*)(EB + (size_t)r * 8192);
      float* wrow = (float*)(WB + (size_t)r * 16384);
      for (int c = lane * 8; c < 4096; c += 512) {
        short8 ev = *(const short8*)(erow + c);
        f32x4 o0, o1;
#pragma unroll
        for (int j = 0; j < 4; ++j) o0[j] = bf2f(ev[j]) * rinv;
#pragma unroll
        for (int j = 0; j < 4; ++j) o1[j] = bf2f(ev[4 + j]) * rinv;
        *(f32x4*)(wrow + c) = o0;
        *(f32x4*)(wrow + c + 4) = o1;
      }
    }
    __syncthreads();
  }
}

// ---------------------------------------------------------------- launch
extern "C" void kernel_launch(void* const* d_in, const int* in_sizes, int n_in,
                              void* d_out, int out_size, void* d_ws, size_t ws_size,
                              hipStream_t stream) {
  const float* x  = (const float*)d_in[0];
  const float* wq = (const float*)d_in[1];
  const float* wk = (const float*)d_in[2];
  const float* wv = (const float*)d_in[3];

  float* out = (float*)d_out;                    // [B][S][D]
  float* wts = out + (size_t)B_ * S_ * D_;       // [B][S][S]

  // workspace layout (~63.5 MB)
  short* xh = (short*)d_ws;
  short* xl = xh + NQ;
  short* qh = xl + NQ;
  short* ql = qh + NQ;
  short* kh = ql + NQ;
  short* kl = kh + NQ;
  short* vt = kl + NQ;                 // [B][D][S] bf16
  short* wh = vt + NQ;                 // [3][D][D] bf16
  short* wl = wh + 3 * NW;
  float* ctab = (float*)(wl + 3 * NW); // [S][128] (cos,sin) fp32

  k0_split<<<dim3((NQ + 3 * NW + NTAB) / 256), 256, 0, stream>>>(
      x, wq, wk, wv, xh, xl, wh, wl, ctab);
  k1_proj<<<dim3(B_ * S_ / 64, 3), 256, 0, stream>>>(
      xh, xl, wh, wl, ctab, qh, ql, kh, kl, vt);
  k2_fused<<<dim3(B_ * S_ / 64), 512, 0, stream>>>(
      qh, ql, kh, kl, vt, wts, out);
}

// Round 3
// 473.573 us; speedup vs baseline: 2.4277x; 1.0275x over previous
//
#include <hip/hip_runtime.h>
#include <hip/hip_bf16.h>
#include <stdint.h>

// RoPEDemoAttention on MI355X (gfx950)
// B=4, S=4096, D=256. fp32 in/out.
// K0: split fp32 -> bf16 hi/lo (x, wq, wk, wv) + build RoPE cos/sin table.
// K1: Q/K/V = X @ W^T via 3-pass split-bf16 MFMA; RoPE via table.
// K2 (fused, software-pipelined): per (b, 64-q-tile):
//   dbuf K-tile LDS + dbuf e-tile, ONE barrier per k-tile:
//     stage(kt+1) -> ecopy+PV(kt-1) -> scores(kt) -> exp -> barrier
//   then rowsums, normalized out, phased in-place e->weights sweep.

#define B_ 4
#define S_ 4096
#define D_ 256
#define NQ 4194304   // B_*S_*D_
#define NW 65536     // D_*D_
#define NTAB 524288  // S_*128 table entries (cos,sin pairs)

typedef __attribute__((ext_vector_type(4))) float f32x4;
typedef __attribute__((ext_vector_type(8))) short short8;
typedef __attribute__((ext_vector_type(4))) short short4v;
typedef __attribute__((ext_vector_type(4))) unsigned uint32x4;

__device__ __forceinline__ short f2bf(float f) {
  unsigned u = __builtin_bit_cast(unsigned, f);
  u += 0x7fffu + ((u >> 16) & 1u);   // RNE
  return (short)(u >> 16);
}
__device__ __forceinline__ float bf2f(short h) {
  unsigned u = ((unsigned)(unsigned short)h) << 16;
  return __builtin_bit_cast(float, u);
}

__device__ __forceinline__ void gload16(const void* g, void* l) {
  __builtin_amdgcn_global_load_lds(
      (const __attribute__((address_space(1))) unsigned*)g,
      (__attribute__((address_space(3))) unsigned*)l, 16, 0, 0);
}

// ------------------------------------------------ K0: split + RoPE table
__global__ __launch_bounds__(256) void k0_split(
    const float* __restrict__ x, const float* __restrict__ wq,
    const float* __restrict__ wk, const float* __restrict__ wv,
    short* __restrict__ xh, short* __restrict__ xl,
    short* __restrict__ wh, short* __restrict__ wl,
    float* __restrict__ ctab) {
  int idx = blockIdx.x * 256 + threadIdx.x;  // grid = NQ + 3*NW + NTAB
  if (idx < NQ) {
    float v = x[idx];
    short hi = f2bf(v);
    xh[idx] = hi;
    xl[idx] = f2bf(v - bf2f(hi));
  } else if (idx < NQ + 3 * NW) {
    int r = idx - NQ;
    int m = r >> 16;
    int e = r & (NW - 1);
    const float* w = (m == 0) ? wq : (m == 1) ? wk : wv;
    float v = w[e];
    short hi = f2bf(v);
    wh[r] = hi;
    wl[r] = f2bf(v - bf2f(hi));
  } else {
    int t = idx - NQ - 3 * NW;          // t < NTAB
    int s = t >> 7, j = t & 127;
    float invf = __expf(-0.07195578415606394f * (float)j); // 10000^(-j/128)
    float sn, cs;
    sincosf((float)s * invf, &sn, &cs);
    ctab[2 * t] = cs;
    ctab[2 * t + 1] = sn;
  }
}

// ------------------------------------------------------- K1: proj + RoPE
__global__ __launch_bounds__(256) void k1_proj(
    const short* __restrict__ xh, const short* __restrict__ xl,
    const short* __restrict__ wh, const short* __restrict__ wl,
    const float* __restrict__ ctab,
    short* __restrict__ qh, short* __restrict__ ql,
    short* __restrict__ kh, short* __restrict__ kl,
    short* __restrict__ vt) {
  const int m = blockIdx.y;                 // 0=q 1=k 2=v
  const int b = blockIdx.x >> 6;
  const int sbase = (blockIdx.x & 63) << 6; // 64-row tile
  const int tid = threadIdx.x;
  const int w = tid >> 6;
  const int lane = tid & 63;
  const int lr = lane & 15;
  const int g = lane >> 4;

  const int srow = sbase + w * 16 + lr;     // A-frag row
  const short* xhp = xh + ((size_t)(b * S_ + srow)) * D_;
  const short* xlp = xl + ((size_t)(b * S_ + srow)) * D_;
  const short* whm = wh + m * NW;
  const short* wlm = wl + m * NW;

  f32x4 acc[16];
#pragma unroll
  for (int i = 0; i < 16; ++i) acc[i] = (f32x4)0.f;

#pragma unroll
  for (int dc = 0; dc < 8; ++dc) {
    const int d = dc * 32 + g * 8;
    short8 ah = *(const short8*)(xhp + d);
    short8 al = *(const short8*)(xlp + d);
#pragma unroll
    for (int ct = 0; ct < 16; ++ct) {
      const int e = ct * 16 + lr;
      short8 bh = *(const short8*)(whm + e * D_ + d);
      short8 bl = *(const short8*)(wlm + e * D_ + d);
      acc[ct] = __builtin_amdgcn_mfma_f32_16x16x32_bf16(ah, bh, acc[ct], 0, 0, 0);
      acc[ct] = __builtin_amdgcn_mfma_f32_16x16x32_bf16(ah, bl, acc[ct], 0, 0, 0);
      acc[ct] = __builtin_amdgcn_mfma_f32_16x16x32_bf16(al, bh, acc[ct], 0, 0, 0);
    }
  }

  const int s0 = sbase + w * 16 + g * 4;    // C/D row base
  if (m == 2) {
#pragma unroll
    for (int ct = 0; ct < 16; ++ct) {
      const int e = ct * 16 + lr;
      short4v pk;
#pragma unroll
      for (int r = 0; r < 4; ++r) pk[r] = f2bf(acc[ct][r]);
      *(short4v*)(vt + ((size_t)(b * D_ + e)) * S_ + s0) = pk;
    }
  } else {
    short* oh = (m == 0) ? qh : kh;
    short* ol = (m == 0) ? ql : kl;
#pragma unroll
    for (int ct = 0; ct < 16; ++ct) {
      const int e = ct * 16 + lr;
      const float sgn = (e & 1) ? 1.0f : -1.0f;  // rotate_half sign
#pragma unroll
      for (int r = 0; r < 4; ++r) {
        float v = acc[ct][r];
        float p = __shfl_xor(v, 1, 64);          // partner e^1, same s
        const float2 cs2 = *(const float2*)(ctab + ((size_t)((s0 + r) << 7) + (e & 127)) * 2);
        float q2 = v * cs2.x + sgn * p * cs2.y;
        short hi = f2bf(q2);
        size_t off = ((size_t)(b * S_ + s0 + r)) * D_ + e;
        oh[off] = hi;
        ol[off] = f2bf(q2 - bf2f(hi));
      }
    }
  }
}

// ------------------- K2 fused: pipelined scores + e-store + PV + sweep
__global__ __launch_bounds__(512, 2) void k2_fused(
    const short* __restrict__ qh, const short* __restrict__ ql,
    const short* __restrict__ kh, const short* __restrict__ kl,
    const short* __restrict__ vt,
    float* __restrict__ wts, float* __restrict__ out) {
  __shared__ __align__(16) char kbuf[131072];   // [2][Khi 32K | Klo 32K]
  __shared__ __align__(16) char etile[2][8192]; // e bf16 [64][64], swizzled
  __shared__ float part[4][64];
  __shared__ float lsum_l[64];

  const int bid = blockIdx.x;
  const int swz = (bid & 7) * 32 + (bid >> 3); // XCD-contiguous (256 = 8*32)
  const int b = swz >> 6;
  const int qbase = (swz & 63) << 6;
  const int tid = threadIdx.x;
  const int w = tid >> 6;        // 8 waves
  const int lane = tid & 63;
  const int lr = lane & 15;
  const int g = lane >> 4;
  const int wq2 = w & 1;         // scores: which 32 q-rows
  const int wk4 = w >> 1;        // scores: which 16 keys of 64-key tile
  const int qh_pv = w & 1;       // PV: q 32-half
  const int dh_pv = w >> 1;      // PV: d 64-quarter

  // Q hi/lo fragments (B-operand), registers for all 64 k-tiles
  short8 qfh[2][8], qfl[2][8];
#pragma unroll
  for (int qt = 0; qt < 2; ++qt) {
    const int qrow = qbase + wq2 * 32 + qt * 16 + lr;
    const short* ph = qh + ((size_t)(b * S_ + qrow)) * D_;
    const short* pl = ql + ((size_t)(b * S_ + qrow)) * D_;
#pragma unroll
    for (int dc = 0; dc < 8; ++dc) {
      qfh[qt][dc] = *(const short8*)(ph + dc * 32 + g * 8);
      qfl[qt][dc] = *(const short8*)(pl + dc * 32 + g * 8);
    }
  }

  f32x4 acc[2];
  acc[0] = (f32x4)0.f; acc[1] = (f32x4)0.f;
  f32x4 accv[2][4];
#pragma unroll
  for (int qt = 0; qt < 2; ++qt)
#pragma unroll
    for (int dt = 0; dt < 4; ++dt) accv[qt][dt] = (f32x4)0.f;
  float rs[2] = {0.f, 0.f};

  const char* khb = (const char*)(kh + (size_t)b * S_ * D_);
  const char* klb = (const char*)(kl + (size_t)b * S_ * D_);
  const short* vtb = vt + (size_t)b * D_ * S_;
  const int keyl = wk4 * 16 + lr;          // local key row of A-frag
  const int swx = (lane & 7) << 4;         // K-LDS swizzle: (key&7)<<4

  // block's weights region (1 MiB); e-bf16 scratch in its top half
  char* WB = (char*)(wts + ((size_t)(b * S_ + qbase)) * S_);
  char* EB = WB + 524288;

  // prologue: stage K-tile 0 into kbuf[0]
#pragma unroll
  for (int i = 0; i < 4; ++i) {
    const int p = i * 8192 + tid * 16;
    const int xo = p ^ (((p >> 9) & 7) << 4);
    gload16(khb + xo, kbuf + p);
    gload16(klb + xo, kbuf + 32768 + p);
  }
  __syncthreads();

  for (int kt = 0; kt < 64; ++kt) {
    const int cur = kt & 1;
    const char* kb = kbuf + cur * 65536;

    // 1. stage next K-tile into the other buffer (lands by end barrier)
    if (kt < 63) {
      const char* sh = khb + (size_t)(kt + 1) * 32768;
      const char* sl = klb + (size_t)(kt + 1) * 32768;
      char* kn = kbuf + (cur ^ 1) * 65536;
#pragma unroll
      for (int i = 0; i < 4; ++i) {
        const int p = i * 8192 + tid * 16;
        const int xo = p ^ (((p >> 9) & 7) << 4);
        gload16(sh + xo, kn + p);
        gload16(sl + xo, kn + 32768 + p);
      }
    }

    // 2. e-copy + PV of the PREVIOUS tile (etile[cur^1])
    if (kt > 0) {
      const char* et = etile[cur ^ 1];
      {
        const int p = tid * 16;            // 512 thr * 16B = 8 KB
        const int row = p >> 7, cb = p & 127;
        uint32x4 v = *(const uint32x4*)(et + (p ^ ((row & 7) << 4)));
        *(uint32x4*)(EB + (size_t)row * 8192 + (kt - 1) * 128 + cb) = v;
      }
      __builtin_amdgcn_s_setprio(1);
#pragma unroll
      for (int kk = 0; kk < 2; ++kk) {
        short8 ea0, ea1;
        {
          const int row = qh_pv * 32 + lr;
          ea0 = *(const short8*)(et + ((row * 128 + kk * 64 + g * 16) ^ ((row & 7) << 4)));
        }
        {
          const int row = qh_pv * 32 + 16 + lr;
          ea1 = *(const short8*)(et + ((row * 128 + kk * 64 + g * 16) ^ ((row & 7) << 4)));
        }
#pragma unroll
        for (int dt = 0; dt < 4; ++dt) {
          const int d = dh_pv * 64 + dt * 16 + lr;
          short8 vb = *(const short8*)(vtb + (size_t)d * S_ + (kt - 1) * 64 + kk * 32 + g * 8);
          accv[0][dt] = __builtin_amdgcn_mfma_f32_16x16x32_bf16(ea0, vb, accv[0][dt], 0, 0, 0);
          accv[1][dt] = __builtin_amdgcn_mfma_f32_16x16x32_bf16(ea1, vb, accv[1][dt], 0, 0, 0);
        }
      }
      __builtin_amdgcn_s_setprio(0);
    }

    // 3. scores: 3-pass split bf16, S^T = K * Q^T (reads kb)
    __builtin_amdgcn_s_setprio(1);
#pragma unroll
    for (int dc = 0; dc < 8; ++dc) {
      const int x = (keyl * 512 + dc * 64 + g * 16) ^ swx;
      short8 afh = *(const short8*)(kb + x);
      short8 afl = *(const short8*)(kb + 32768 + x);
      acc[0] = __builtin_amdgcn_mfma_f32_16x16x32_bf16(afh, qfh[0][dc], acc[0], 0, 0, 0);
      acc[0] = __builtin_amdgcn_mfma_f32_16x16x32_bf16(afh, qfl[0][dc], acc[0], 0, 0, 0);
      acc[0] = __builtin_amdgcn_mfma_f32_16x16x32_bf16(afl, qfh[0][dc], acc[0], 0, 0, 0);
      acc[1] = __builtin_amdgcn_mfma_f32_16x16x32_bf16(afh, qfh[1][dc], acc[1], 0, 0, 0);
      acc[1] = __builtin_amdgcn_mfma_f32_16x16x32_bf16(afh, qfl[1][dc], acc[1], 0, 0, 0);
      acc[1] = __builtin_amdgcn_mfma_f32_16x16x32_bf16(afl, qfh[1][dc], acc[1], 0, 0, 0);
    }
    __builtin_amdgcn_s_setprio(0);

    // 4. e = exp(s/16) -> etile[cur] (bf16, swizzled) + rowsum
#pragma unroll
    for (int qt = 0; qt < 2; ++qt) {
      f32x4 e;
#pragma unroll
      for (int r = 0; r < 4; ++r) e[r] = __expf(acc[qt][r] * 0.0625f);
      rs[qt] += e[0] + e[1] + e[2] + e[3];
      unsigned lo = (unsigned)(unsigned short)f2bf(e[0]) |
                    ((unsigned)(unsigned short)f2bf(e[1]) << 16);
      unsigned hi2 = (unsigned)(unsigned short)f2bf(e[2]) |
                     ((unsigned)(unsigned short)f2bf(e[3]) << 16);
      const int row = wq2 * 32 + qt * 16 + lr;
      const int colb = (wk4 * 16 + g * 4) * 2;
      const int ad = (row * 128 + colb) ^ ((row & 7) << 4);
      *(uint2*)(etile[cur] + ad) = make_uint2(lo, hi2);
      acc[qt] = (f32x4)0.f;
    }
    __syncthreads();   // ONE barrier per tile
  }

  // ---- tail: e-copy + PV of tile 63 (etile[1])
  {
    const char* et = etile[1];
    {
      const int p = tid * 16;
      const int row = p >> 7, cb = p & 127;
      uint32x4 v = *(const uint32x4*)(et + (p ^ ((row & 7) << 4)));
      *(uint32x4*)(EB + (size_t)row * 8192 + 63 * 128 + cb) = v;
    }
#pragma unroll
    for (int kk = 0; kk < 2; ++kk) {
      short8 ea0, ea1;
      {
        const int row = qh_pv * 32 + lr;
        ea0 = *(const short8*)(et + ((row * 128 + kk * 64 + g * 16) ^ ((row & 7) << 4)));
      }
      {
        const int row = qh_pv * 32 + 16 + lr;
        ea1 = *(const short8*)(et + ((row * 128 + kk * 64 + g * 16) ^ ((row & 7) << 4)));
      }
#pragma unroll
      for (int dt = 0; dt < 4; ++dt) {
        const int d = dh_pv * 64 + dt * 16 + lr;
        short8 vb = *(const short8*)(vtb + (size_t)d * S_ + 63 * 64 + kk * 32 + g * 8);
        accv[0][dt] = __builtin_amdgcn_mfma_f32_16x16x32_bf16(ea0, vb, accv[0][dt], 0, 0, 0);
        accv[1][dt] = __builtin_amdgcn_mfma_f32_16x16x32_bf16(ea1, vb, accv[1][dt], 0, 0, 0);
      }
    }
  }

  // ---- rowsums -> lsum_l
#pragma unroll
  for (int qt = 0; qt < 2; ++qt) {
    rs[qt] += __shfl_xor(rs[qt], 16, 64);
    rs[qt] += __shfl_xor(rs[qt], 32, 64);
  }
  if (lane < 16) {
    part[wk4][wq2 * 32 + lane] = rs[0];
    part[wk4][wq2 * 32 + 16 + lane] = rs[1];
  }
  __syncthreads();   // also drains tail EB stores (vmcnt)
  if (tid < 64)
    lsum_l[tid] = part[0][tid] + part[1][tid] + part[2][tid] + part[3][tid];
  __syncthreads();

  // ---- copy e rows 62,63 into LDS (their EB copies are overwritten last)
#pragma unroll
  for (int i = 0; i < 2; ++i) {
    const int p = i * 8192 + tid * 16;
    *(uint32x4*)(kbuf + p) = *(const uint32x4*)(EB + (size_t)62 * 8192 + p);
  }

  // ---- normalized output write
  {
    float* ob = out + (size_t)b * S_ * D_;
    float rv[2][4];
#pragma unroll
    for (int qt = 0; qt < 2; ++qt)
#pragma unroll
      for (int r = 0; r < 4; ++r)
        rv[qt][r] = 1.0f / lsum_l[qh_pv * 32 + qt * 16 + g * 4 + r];
#pragma unroll
    for (int qt = 0; qt < 2; ++qt)
#pragma unroll
      for (int dt = 0; dt < 4; ++dt)
#pragma unroll
        for (int r = 0; r < 4; ++r) {
          const int q = qbase + qh_pv * 32 + qt * 16 + g * 4 + r;
          ob[(size_t)q * D_ + dh_pv * 64 + dt * 16 + lr] = accv[qt][dt][r] * rv[qt][r];
        }
  }
  __syncthreads();

  // ---- phased in-place normalize sweep: e-bf16 (EB) -> f32 weights (WB)
  const int pr0[6] = {0, 32, 48, 56, 60, 62};
  const int pr1[6] = {32, 48, 56, 60, 62, 64};
#pragma unroll 1
  for (int ph = 0; ph < 6; ++ph) {
    for (int r = pr0[ph] + w; r < pr1[ph]; r += 8) {
      const float rinv = 1.0f / lsum_l[r];
      const short* erow = (r >= 62) ? (const short*)(kbuf + (size_t)(r - 62) * 8192)
                                    : (const short*)(EB + (size_t)r * 8192);
      float* wrow = (float*)(WB + (size_t)r * 16384);
      for (int c = lane * 8; c < 4096; c += 512) {
        short8 ev = *(const short8*)(erow + c);
        f32x4 o0, o1;
#pragma unroll
        for (int j = 0; j < 4; ++j) o0[j] = bf2f(ev[j]) * rinv;
#pragma unroll
        for (int j = 0; j < 4; ++j) o1[j] = bf2f(ev[4 + j]) * rinv;
        *(f32x4*)(wrow + c) = o0;
        *(f32x4*)(wrow + c + 4) = o1;
      }
    }
    __syncthreads();
  }
}

// ---------------------------------------------------------------- launch
extern "C" void kernel_launch(void* const* d_in, const int* in_sizes, int n_in,
                              void* d_out, int out_size, void* d_ws, size_t ws_size,
                              hipStream_t stream) {
  const float* x  = (const float*)d_in[0];
  const float* wq = (const float*)d_in[1];
  const float* wk = (const float*)d_in[2];
  const float* wv = (const float*)d_in[3];

  float* out = (float*)d_out;                    // [B][S][D]
  float* wts = out + (size_t)B_ * S_ * D_;       // [B][S][S]

  // workspace layout (~63.5 MB)
  short* xh = (short*)d_ws;
  short* xl = xh + NQ;
  short* qh = xl + NQ;
  short* ql = qh + NQ;
  short* kh = ql + NQ;
  short* kl = kh + NQ;
  short* vt = kl + NQ;                 // [B][D][S] bf16
  short* wh = vt + NQ;                 // [3][D][D] bf16
  short* wl = wh + 3 * NW;
  float* ctab = (float*)(wl + 3 * NW); // [S][128] (cos,sin) fp32

  k0_split<<<dim3((NQ + 3 * NW + NTAB) / 256), 256, 0, stream>>>(
      x, wq, wk, wv, xh, xl, wh, wl, ctab);
  k1_proj<<<dim3(B_ * S_ / 64, 3), 256, 0, stream>>>(
      xh, xl, wh, wl, ctab, qh, ql, kh, kl, vt);
  k2_fused<<<dim3(B_ * S_ / 64), 512, 0, stream>>>(
      qh, ql, kh, kl, vt, wts, out);
}